// Round 18
// baseline (472.755 us; speedup 1.0000x reference)
//
#include <hip/hip_runtime.h>
#include <hip/hip_bf16.h>

typedef unsigned short u16;
typedef __attribute__((ext_vector_type(8))) short short8v;          // 8 bf16 (4 VGPRs)
typedef __attribute__((ext_vector_type(8))) unsigned short u16x8;   // 8 u16
typedef __attribute__((ext_vector_type(4))) float f32x4;

#define HWPIX 65536  // 256*256
#define AS1(p) ((const __attribute__((address_space(1))) void*)(p))
#define AS3(p) ((__attribute__((address_space(3))) void*)(p))

__device__ __forceinline__ float bfbits2f(u16 u) {
  return __uint_as_float(((unsigned)u) << 16);
}
__device__ __forceinline__ float4 ld4bf(const u16* p) {
  ushort4 u = *(const ushort4*)(const void*)p;
  return make_float4(bfbits2f(u.x), bfbits2f(u.y), bfbits2f(u.z), bfbits2f(u.w));
}
__device__ __forceinline__ u16 f2bf(float f) {
  union { __hip_bfloat16 h; u16 u; } c;
  c.h = __float2bfloat16(f);   // RNE
  return c.u;
}
// tanh-form gelu: |err| <= ~3e-4 abs; reaches d_out only via 0.02^2-damped FFN path.
__device__ __forceinline__ float gelu_f(float x) {
  float z = 0.79788456f * x * (1.0f + 0.044715f * x * x);
  float e = __expf(2.0f * z);
  float th = 1.0f - 2.0f * __builtin_amdgcn_rcpf(e + 1.0f);
  return 0.5f * x * (1.0f + th);
}
// apply BN scale/shift to 8 bf16 at channel kk..kk+7, re-round to bf16
__device__ __forceinline__ u16x8 bn8(u16x8 v, const float* __restrict__ sc,
                                     const float* __restrict__ sh, int kk) {
  float4 s0 = *(const float4*)&sc[kk], s1 = *(const float4*)&sc[kk + 4];
  float4 t0 = *(const float4*)&sh[kk], t1 = *(const float4*)&sh[kk + 4];
  u16x8 r;
  r[0] = f2bf(bfbits2f(v[0]) * s0.x + t0.x); r[1] = f2bf(bfbits2f(v[1]) * s0.y + t0.y);
  r[2] = f2bf(bfbits2f(v[2]) * s0.z + t0.z); r[3] = f2bf(bfbits2f(v[3]) * s0.w + t0.w);
  r[4] = f2bf(bfbits2f(v[4]) * s1.x + t1.x); r[5] = f2bf(bfbits2f(v[5]) * s1.y + t1.y);
  r[6] = f2bf(bfbits2f(v[6]) * s1.z + t1.z); r[7] = f2bf(bfbits2f(v[7]) * s1.w + t1.w);
  return r;
}

// ------ unified prep: nhwc transform (blocks 0..4095) + weight pack/convert (4096..4656) ------
__launch_bounds__(256)
__global__ void prep_k(const float* __restrict__ feat, u16* __restrict__ featb,
                       const float* __restrict__ w0, const float* __restrict__ w1,
                       const float* __restrict__ w2, const float* __restrict__ b0,
                       const float* __restrict__ b1, const float* __restrict__ b2,
                       const float* __restrict__ wf1, const float* __restrict__ wf2,
                       u16* __restrict__ wT, float* __restrict__ bias192,
                       u16* __restrict__ wf1b, u16* __restrict__ wf2b) {
  __shared__ float tile[64][65];
  const int t = threadIdx.x;
  const int bxg = blockIdx.x;
  if (bxg < 4096) {
    const int xs = (bxg & 3) << 6, yy = (bxg >> 2) & 255, b = bxg >> 10;
#pragma unroll
    for (int it = 0; it < 4; ++it) {
      const int idx = t + it * 256;
      const int c = idx >> 4, seg = (idx & 15) << 2;
      float4 v = *(const float4*)&feat[(((size_t)(b * 64 + c)) << 16) + yy * 256 + xs + seg];
      tile[c][seg] = v.x; tile[c][seg + 1] = v.y; tile[c][seg + 2] = v.z; tile[c][seg + 3] = v.w;
    }
    __syncthreads();
#pragma unroll
    for (int it = 0; it < 4; ++it) {
      const int idx = t + it * 256;
      const int cs = (idx & 15) << 2, px = idx >> 4;
      ushort4 r;
      r.x = f2bf(tile[cs + 0][px]); r.y = f2bf(tile[cs + 1][px]);
      r.z = f2bf(tile[cs + 2][px]); r.w = f2bf(tile[cs + 3][px]);
      *(ushort4*)&featb[(((size_t)((b * 256 + yy) * 256 + xs + px)) << 6) + cs] = r;
    }
    return;
  }
  const int bx = bxg - 4096;
  if (bx >= 497) {
    const int e = (bx - 497) * 256 + t;
    wf2b[e] = f2bf(wf2[e]);
    return;
  }
  if (bx >= 433) {
    const int e = (bx - 433) * 256 + t;
    wf1b[e] = f2bf(wf1[e]);
    return;
  }
  if (bx == 432) {
    if (t < 192) {
      const float* bp = (t < 64) ? b0 : (t < 128) ? b1 : b2;
      bias192[t] = bp[t & 63];
    }
    return;
  }
  const int e = bx * 256 + t;
  const int pos = e / 12288, rem = e % 12288;
  const int n = rem >> 6, ic = rem & 63;
  const int conv = n >> 6, oc = n & 63;
  const float* wp = (conv == 0) ? w0 : (conv == 1) ? w1 : w2;
  wT[e] = f2bf(wp[(oc * 64 + ic) * 9 + pos]);
}

// ---------------- f32 -> bf16 bulk convert, dual (z selects src/dst) ----------------
__launch_bounds__(256)
__global__ void wcvt2_k(const float* __restrict__ s0, u16* __restrict__ d0,
                        const float* __restrict__ s1, u16* __restrict__ d1) {
  const float* src = blockIdx.y ? s1 : s0;
  u16* dst = blockIdx.y ? d1 : d0;
  const int i = (blockIdx.x * 256 + threadIdx.x) << 2;
  float4 v = *(const float4*)&src[i];
  ushort4 r;
  r.x = f2bf(v.x); r.y = f2bf(v.y); r.z = f2bf(v.z); r.w = f2bf(v.w);
  *(ushort4*)&dst[i] = r;
}

// ---------------- fused 3-conv implicit GEMM (MFMA), XOR-swizzled LDS + reg-prefetch ----------------
__launch_bounds__(256)
__global__ void convmfma_k(const u16* __restrict__ featb, const u16* __restrict__ wT,
                           const float* __restrict__ bias192, u16* __restrict__ qun,
                           u16* __restrict__ kun, u16* __restrict__ vT) {
  __shared__ u16 As[128 * 64];   // 16 KB
  __shared__ u16 Bs[192 * 64];   // 24 KB
  const int tid = threadIdx.x;
  const int lin = blockIdx.x;
  const int virt = (lin & 7) * 256 + (lin >> 3);
  const int b = virt >> 9, yy = (virt >> 1) & 255, x0 = (virt & 1) << 7;
  const int lane = tid & 63, w = tid >> 6;
  const int wm = w >> 1, wn = w & 1;

  u16x8 rA[4], rB[6];
  auto issue = [&](int pos) {
    const int dy = pos / 3, dx = pos % 3;
    const int yp = yy + dy - 1;
    const bool yok = (unsigned)yp < 256u;
#pragma unroll
    for (int i = 0; i < 4; ++i) {
      const int slot = tid + (i << 8);
      const int row = slot >> 3, cg = slot & 7;
      const int xp = x0 + row + dx - 1;
      u16x8 v{};
      if (yok && (unsigned)xp < 256u)
        v = *(const u16x8*)&featb[(((size_t)((b * 256 + yp) * 256 + xp)) << 6) + (cg << 3)];
      rA[i] = v;
    }
    const u16* wb = wT + (size_t)pos * 12288;
#pragma unroll
    for (int i = 0; i < 6; ++i) {
      const int slot = tid + (i << 8);
      const int row = slot >> 3, cg = slot & 7;
      rB[i] = *(const u16x8*)&wb[(row << 6) + (cg << 3)];
    }
  };
  auto commit = [&]() {
#pragma unroll
    for (int i = 0; i < 4; ++i) {
      const int slot = tid + (i << 8);
      const int row = slot >> 3, cg = slot & 7;
      *(u16x8*)&As[(row << 6) + ((cg ^ (row & 7)) << 3)] = rA[i];
    }
#pragma unroll
    for (int i = 0; i < 6; ++i) {
      const int slot = tid + (i << 8);
      const int row = slot >> 3, cg = slot & 7;
      *(u16x8*)&Bs[(row << 6) + ((cg ^ (row & 7)) << 3)] = rB[i];
    }
  };

  f32x4 acc[4][6] = {};
  const int kc = (lane >> 4) << 3;
  const int afr = wm * 64 + (lane & 15);
  const int bfr0 = wn * 96 + (lane & 15);

  issue(0);
  commit();
  __syncthreads();

  for (int pos = 0; pos < 9; ++pos) {
    if (pos + 1 < 9) issue(pos + 1);
#pragma unroll
    for (int ks = 0; ks < 2; ++ks) {
      const int ce = (ks << 5) + kc;
      short8v a[4], bf[6];
#pragma unroll
      for (int f = 0; f < 4; ++f) {
        const int row = afr + f * 16;
        a[f] = *(const short8v*)&As[(row << 6) + (ce ^ ((row & 7) << 3))];
      }
#pragma unroll
      for (int f = 0; f < 6; ++f) {
        const int row = bfr0 + f * 16;
        bf[f] = *(const short8v*)&Bs[(row << 6) + (ce ^ ((row & 7) << 3))];
      }
#pragma unroll
      for (int i = 0; i < 4; ++i)
#pragma unroll
        for (int j = 0; j < 6; ++j)
          acc[i][j] = __builtin_amdgcn_mfma_f32_16x16x32_bf16(a[i], bf[j], acc[i][j], 0, 0, 0);
    }
    __syncthreads();
    if (pos + 1 < 9) {
      commit();
      __syncthreads();
    }
  }

  const int py = yy >> 3, ky = yy & 7;
  const int rp0 = wm * 64 + ((lane >> 4) << 2);
#pragma unroll
  for (int j = 0; j < 6; ++j) {
    const int colb = wn * 96 + j * 16;
    const int conv = colb >> 6;
    const int oc = (colb & 63) + (lane & 15);
    const float bj = bias192[colb + (lane & 15)];
#pragma unroll
    for (int i = 0; i < 4; ++i) {
      const int rp = rp0 + i * 16;
      const int xg = x0 + rp;
      const int px = xg >> 3, kx0 = xg & 7;
      float v0 = gelu_f(acc[i][j][0] + bj);
      float v1 = gelu_f(acc[i][j][1] + bj);
      float v2 = gelu_f(acc[i][j][2] + bj);
      float v3 = gelu_f(acc[i][j][3] + bj);
      const int d0 = (oc << 6) + (ky << 3) + kx0;
      if (conv < 2) {
        u16* dst = conv ? kun : qun;
        const size_t addr = (((size_t)((b << 10) + py * 32 + px)) << 12) + d0;
        ushort4 r4;
        r4.x = f2bf(v0); r4.y = f2bf(v1); r4.z = f2bf(v2); r4.w = f2bf(v3);
        *(ushort4*)&dst[addr] = r4;
      } else {
        const int m = py * 32 + px;
        const size_t base = (((size_t)(b * 4096 + d0)) << 10) + m;
        vT[base] = f2bf(v0);
        vT[base + 1024] = f2bf(v1);
        vT[base + 2048] = f2bf(v2);
        vT[base + 3072] = f2bf(v3);
      }
    }
  }
}

// ---------------- BN stats, two-stage parallel reduction ----------------
__launch_bounds__(256)
__global__ void bnpart_k(const u16* __restrict__ q, const u16* __restrict__ k,
                         float2* __restrict__ part) {
  const u16* x = blockIdx.y ? k : q;
  const int b = blockIdx.x, t = threadIdx.x;
  const int c = t << 2;
  float s0 = 0.f, s1 = 0.f, s2 = 0.f, s3 = 0.f;
  float q0 = 0.f, q1 = 0.f, q2 = 0.f, q3 = 0.f;
  const u16* base = x + ((size_t)b << 15) + c;
#pragma unroll 4
  for (int r = 0; r < 32; ++r) {
    float4 v = ld4bf(base + (r << 10));
    s0 += v.x; q0 += v.x * v.x;
    s1 += v.y; q1 += v.y * v.y;
    s2 += v.z; q2 += v.z * v.z;
    s3 += v.w; q3 += v.w * v.w;
  }
  float2* dst = part + (((size_t)(blockIdx.y * 128 + b)) << 10) + c;
  dst[0] = make_float2(s0, q0);
  dst[1] = make_float2(s1, q1);
  dst[2] = make_float2(s2, q2);
  dst[3] = make_float2(s3, q3);
}
__launch_bounds__(256)
__global__ void bnfin_k(const float2* __restrict__ part, const float* __restrict__ gq,
                        const float* __restrict__ betaq, const float* __restrict__ gk,
                        const float* __restrict__ betak, float* __restrict__ scq,
                        float* __restrict__ shq, float* __restrict__ sck,
                        float* __restrict__ shk) {
  const int n = blockIdx.x * 256 + threadIdx.x;
  const int y = blockIdx.y;
  const float2* p = part + (((size_t)(y * 128)) << 10) + n;
  float S = 0.f, S2 = 0.f;
  for (int i = 0; i < 128; ++i) {
    float2 v = p[(size_t)i << 10];
    S += v.x; S2 += v.y;
  }
  const float mean = S * (1.0f / 4096.0f);
  const float var = S2 * (1.0f / 4096.0f) - mean * mean;  // biased, matches torch fwd
  const float rstd = rsqrtf(var + 1e-5f);
  const float g = (y ? gk : gq)[n];
  const float be = (y ? betak : betaq)[n];
  const float sc = g * rstd;
  (y ? sck : scq)[n] = sc;
  (y ? shk : shq)[n] = be - mean * sc;
}

// ---------------- row softmax over [4096 rows][1024] bf16 in place ----------------
__launch_bounds__(256)
__global__ void softmax_k(u16* __restrict__ s) {
  u16* p = s + (size_t)blockIdx.x * 1024;
  const int tid = threadIdx.x;
  float4 v = ld4bf(p + (tid << 2));
  float mx = fmaxf(fmaxf(v.x, v.y), fmaxf(v.z, v.w));
#pragma unroll
  for (int off = 32; off > 0; off >>= 1) mx = fmaxf(mx, __shfl_xor(mx, off));
  __shared__ float red[8];
  if ((tid & 63) == 0) red[tid >> 6] = mx;
  __syncthreads();
  mx = fmaxf(fmaxf(red[0], red[1]), fmaxf(red[2], red[3]));
  float e0 = __expf(v.x - mx), e1 = __expf(v.y - mx), e2 = __expf(v.z - mx), e3 = __expf(v.w - mx);
  float sm = e0 + e1 + e2 + e3;
#pragma unroll
  for (int off = 32; off > 0; off >>= 1) sm += __shfl_xor(sm, off);
  if ((tid & 63) == 0) red[4 + (tid >> 6)] = sm;
  __syncthreads();
  sm = red[4] + red[5] + red[6] + red[7];
  float inv = 1.0f / sm;
  ushort4 r;
  r.x = f2bf(e0 * inv); r.y = f2bf(e1 * inv); r.z = f2bf(e2 * inv); r.w = f2bf(e3 * inv);
  *(ushort4*)&p[tid << 2] = r;
}

// ---- 8-wave MFMA GEMM, m97 geometry: BK=32, 32 KB LDS (4 blocks/CU), gload_lds(16B),
// 2-bit chunk XOR swizzle (chunk ^= (row>>1)&3) on source AND fragment reads (modes 0/2) ----
template <int MODE>
__launch_bounds__(512)
__global__ void mgemmL_k(const u16* __restrict__ Ap0, const u16* __restrict__ Bp0,
                         const float* __restrict__ bias0, u16* __restrict__ Cp0, int K,
                         const u16* __restrict__ Ap2, const u16* __restrict__ Bp2,
                         const float* __restrict__ bias2, u16* __restrict__ Cp2) {
  constexpr int SD = (MODE == 0) ? 4096 : 1024;
  __shared__ u16 As[2][128 * 32];   // 8 KB each buf
  __shared__ u16 Bs[2][128 * 32];
  const int tid = threadIdx.x;

  int bx, by, z;
  if constexpr (MODE == 2) {
    int lin = blockIdx.x + 32 * blockIdx.y + 256 * blockIdx.z;
    int sw = (lin & 7) * 128 + (lin >> 3);
    bx = sw & 31; by = (sw >> 5) & 7; z = sw >> 8;
  } else {
    bx = blockIdx.x; by = blockIdx.y; z = blockIdx.z;
  }
  const u16* Ap = Ap0;
  const u16* Bp = Bp0;
  const float* bias = bias0;
  u16* Cp = Cp0;
  if constexpr (MODE == 0) {
    if (z) { Ap = Ap2; Bp = Bp2; bias = bias2; Cp = Cp2; }
  }
  const int m0 = by * 128, n0 = bx * 128;
  const int lane = tid & 63, w = tid >> 6;
  const int wm = w >> 2, wn = w & 3;

  // staging: thread -> (row = tid>>2 in 0..127, chunk = tid&3); source col pre-swizzled
  const int srow = tid >> 2;
  const int scol = (((tid & 3) ^ ((srow >> 1) & 3)) << 3);
  const size_t zoffA = (MODE == 0) ? 0 : ((size_t)z << 10);
  const size_t zoffB = (MODE == 0) ? 0 : ((size_t)z << 12);
  const u16* gA = Ap + (zoffA + m0 + srow) * (size_t)SD + scol;
  const u16* gB = Bp + (zoffB + n0 + srow) * (size_t)SD + scol;
  const int lwb = w * 512;                 // wave-uniform LDS elem base (rows 16w..16w+15)

  const int NT = K >> 5;
  __builtin_amdgcn_global_load_lds(AS1(gA), AS3(&As[0][lwb]), 16, 0, 0);
  __builtin_amdgcn_global_load_lds(AS1(gB), AS3(&Bs[0][lwb]), 16, 0, 0);

  f32x4 acc[4][2] = {};
  const int fr = lane & 15;
  const int kg = (lane >> 4) << 3;
  const int colsw = kg ^ (((fr >> 1) & 3) << 3);   // lane-constant swizzled read col
  int cur = 0;
  for (int t = 0; t < NT; ++t) {
    __syncthreads();                       // drains vmcnt -> buf[cur] valid
    if (t + 1 < NT) {
      const int kn = (t + 1) << 5;
      __builtin_amdgcn_global_load_lds(AS1(gA + kn), AS3(&As[cur ^ 1][lwb]), 16, 0, 0);
      __builtin_amdgcn_global_load_lds(AS1(gB + kn), AS3(&Bs[cur ^ 1][lwb]), 16, 0, 0);
    }
    const u16* Asb = As[cur];
    const u16* Bsb = Bs[cur];
    short8v a[4], bfr[2];
#pragma unroll
    for (int f = 0; f < 4; ++f)
      a[f] = *(const short8v*)&Asb[(wm * 64 + fr + f * 16) * 32 + colsw];
#pragma unroll
    for (int f = 0; f < 2; ++f)
      bfr[f] = *(const short8v*)&Bsb[(wn * 32 + fr + f * 16) * 32 + colsw];
#pragma unroll
    for (int i = 0; i < 4; ++i)
#pragma unroll
      for (int j = 0; j < 2; ++j)
        acc[i][j] = __builtin_amdgcn_mfma_f32_16x16x32_bf16(a[i], bfr[j], acc[i][j], 0, 0, 0);
    cur ^= 1;
  }

  const int rowbase = m0 + wm * 64 + ((lane >> 4) << 2);
  const int colbase = n0 + wn * 32 + (lane & 15);
  if constexpr (MODE == 2) {
    const size_t coff = (size_t)(8 + 8 * z) * 524288;  // ws MiB offsets {8,16,24,32} in u16
    u16* C = Cp + coff;
#pragma unroll
    for (int j = 0; j < 2; ++j) {
      const int d = colbase + j * 16;
      const int c = d >> 6, ky = (d >> 3) & 7, kx = d & 7;
#pragma unroll
      for (int i = 0; i < 4; ++i)
#pragma unroll
        for (int r = 0; r < 4; ++r) {
          const int l = rowbase + i * 16 + r;
          const int p = (((l >> 5) << 3) + ky) * 256 + ((l & 31) << 3) + kx;
          C[((size_t)p << 6) + c] = f2bf(acc[i][j][r]);
        }
    }
  } else {
#pragma unroll
    for (int j = 0; j < 2; ++j) {
      const int col = colbase + j * 16;
      const float bj = bias[col];
#pragma unroll
      for (int i = 0; i < 4; ++i)
#pragma unroll
        for (int r = 0; r < 4; ++r)
          Cp[(size_t)(rowbase + i * 16 + r) * 1024 + col] = f2bf(acc[i][j][r] + bj);
    }
  }
}

// ---------------- 8-wave reg-staged MFMA GEMM (MODE 1 only: BN fused at staging) ----------------
__launch_bounds__(512)
__global__ void mgemm1_k(const u16* __restrict__ Ap, const u16* __restrict__ Bp,
                         const float* __restrict__ sA, const float* __restrict__ hA,
                         const float* __restrict__ sB, const float* __restrict__ hB,
                         u16* __restrict__ Cp, int K) {
  constexpr int SD = 1024;
  __shared__ u16 As[2][128 * 72];
  __shared__ u16 Bs[2][128 * 72];
  const int tid = threadIdx.x;
  const int bx = blockIdx.x, by = blockIdx.y, z = blockIdx.z;
  const int m0 = by * 128, n0 = bx * 128;
  const int lane = tid & 63, w = tid >> 6;
  const int wm = w >> 2, wn = w & 3;

  const int srow = tid >> 3;
  const int scol = (tid & 7) << 3;
  const size_t zoff = (size_t)z << 10;
  const u16* A0 = Ap + (zoff + m0 + srow) * (size_t)SD + scol;
  const u16* A1 = A0 + (size_t)64 * SD;
  const u16* B0 = Bp + (zoff + n0 + srow) * (size_t)SD + scol;
  const u16* B1 = B0 + (size_t)64 * SD;
  const int l0 = srow * 72 + scol;
  const int l1 = (srow + 64) * 72 + scol;

  const int NT = K >> 6;
  u16x8 pA0 = bn8(*(const u16x8*)A0, sA, hA, scol);
  u16x8 pA1 = bn8(*(const u16x8*)A1, sA, hA, scol);
  u16x8 pB0 = bn8(*(const u16x8*)B0, sB, hB, scol);
  u16x8 pB1 = bn8(*(const u16x8*)B1, sB, hB, scol);
  *(u16x8*)&As[0][l0] = pA0; *(u16x8*)&As[0][l1] = pA1;
  *(u16x8*)&Bs[0][l0] = pB0; *(u16x8*)&Bs[0][l1] = pB1;
  __syncthreads();

  f32x4 acc[4][2] = {};
  int cur = 0;
  for (int t = 0; t < NT; ++t) {
    const int kn = (t + 1) << 6;
    if (t + 1 < NT) {
      pA0 = *(const u16x8*)(A0 + kn);
      pA1 = *(const u16x8*)(A1 + kn);
      pB0 = *(const u16x8*)(B0 + kn);
      pB1 = *(const u16x8*)(B1 + kn);
    }
    const u16* Asb = As[cur];
    const u16* Bsb = Bs[cur];
#pragma unroll
    for (int ks = 0; ks < 2; ++ks) {
      const int kc = ks * 32 + ((lane >> 4) << 3);
      short8v a[4], bfr[2];
#pragma unroll
      for (int f = 0; f < 4; ++f)
        a[f] = *(const short8v*)&Asb[(wm * 64 + (lane & 15) + f * 16) * 72 + kc];
#pragma unroll
      for (int f = 0; f < 2; ++f)
        bfr[f] = *(const short8v*)&Bsb[(wn * 32 + (lane & 15) + f * 16) * 72 + kc];
#pragma unroll
      for (int i = 0; i < 4; ++i)
#pragma unroll
        for (int j = 0; j < 2; ++j)
          acc[i][j] = __builtin_amdgcn_mfma_f32_16x16x32_bf16(a[i], bfr[j], acc[i][j], 0, 0, 0);
    }
    if (t + 1 < NT) {
      pA0 = bn8(pA0, sA, hA, kn + scol); pA1 = bn8(pA1, sA, hA, kn + scol);
      pB0 = bn8(pB0, sB, hB, kn + scol); pB1 = bn8(pB1, sB, hB, kn + scol);
      *(u16x8*)&As[cur ^ 1][l0] = pA0; *(u16x8*)&As[cur ^ 1][l1] = pA1;
      *(u16x8*)&Bs[cur ^ 1][l0] = pB0; *(u16x8*)&Bs[cur ^ 1][l1] = pB1;
    }
    __syncthreads();
    cur ^= 1;
  }

  const int rowbase = m0 + wm * 64 + ((lane >> 4) << 2);
  const int colbase = n0 + wn * 32 + (lane & 15);
#pragma unroll
  for (int j = 0; j < 2; ++j) {
    const int col = colbase + j * 16;
#pragma unroll
    for (int i = 0; i < 4; ++i)
#pragma unroll
      for (int r = 0; r < 4; ++r) {
        const size_t row = ((size_t)z << 10) + rowbase + i * 16 + r;
        Cp[row * 1024 + col] = f2bf(acc[i][j][r] * 0.03125f);
      }
  }
}

// ---------------- fused FFN: out = gelu(gelu(fold @ W1^T + b1) @ W2^T + b2) + feat ----------------
__launch_bounds__(512)
__global__ void ffn_k(const u16* __restrict__ fold, const u16* __restrict__ w1b,
                      const u16* __restrict__ w2b, const float* __restrict__ b1,
                      const float* __restrict__ b2, const float* __restrict__ feat,
                      float* __restrict__ out) {
  extern __shared__ u16 sh[];
  u16* Ash = sh;              // [128][72]
  u16* W1s = sh + 9216;       // [256][72]
  u16* mids = sh;             // [128][264] aliased after GEMM1
  const int t = threadIdx.x;
  const int px0 = blockIdx.x << 7;
  const int z = blockIdx.y;
  const u16* fz = fold + ((size_t)z << 22);  // chunks 8 MiB apart (4M u16)

  {  // stage A: 128 x 64
    const int row = t >> 2, cs = (t & 3) << 4;
    const u16* src = fz + (((size_t)(px0 + row)) << 6) + cs;
    *(u16x8*)&Ash[row * 72 + cs] = *(const u16x8*)src;
    *(u16x8*)&Ash[row * 72 + cs + 8] = *(const u16x8*)(src + 8);
  }
  {  // stage W1: 256 x 64
    const int row = t >> 1, cs = (t & 1) << 5;
    const u16* src = w1b + (((size_t)row) << 6) + cs;
    *(u16x8*)&W1s[row * 72 + cs] = *(const u16x8*)src;
    *(u16x8*)&W1s[row * 72 + cs + 8] = *(const u16x8*)(src + 8);
    *(u16x8*)&W1s[row * 72 + cs + 16] = *(const u16x8*)(src + 16);
    *(u16x8*)&W1s[row * 72 + cs + 24] = *(const u16x8*)(src + 24);
  }
  __syncthreads();

  const int lane = t & 63, w = t >> 6;
  const int kc = (lane >> 4) << 3;
  const int mrow = w * 16 + (lane & 15);
  f32x4 acc1[16] = {};
  short8v a0 = *(const short8v*)&Ash[mrow * 72 + kc];
  short8v a1 = *(const short8v*)&Ash[mrow * 72 + 32 + kc];
#pragma unroll
  for (int n = 0; n < 16; ++n) {
    const int br = n * 16 + (lane & 15);
    short8v b0 = *(const short8v*)&W1s[br * 72 + kc];
    short8v bv = *(const short8v*)&W1s[br * 72 + 32 + kc];
    acc1[n] = __builtin_amdgcn_mfma_f32_16x16x32_bf16(a0, b0, acc1[n], 0, 0, 0);
    acc1[n] = __builtin_amdgcn_mfma_f32_16x16x32_bf16(a1, bv, acc1[n], 0, 0, 0);
  }
  __syncthreads();  // Ash/W1s dead; sh becomes mids

  const int mrow0 = w * 16 + ((lane >> 4) << 2);
#pragma unroll
  for (int n = 0; n < 16; ++n) {
    const int col = n * 16 + (lane & 15);
    const float bj = b1[col];
#pragma unroll
    for (int r = 0; r < 4; ++r)
      mids[(mrow0 + r) * 264 + col] = f2bf(gelu_f(acc1[n][r] + bj));
  }
  __syncthreads();

  f32x4 acc2[4] = {};
#pragma unroll
  for (int ks = 0; ks < 8; ++ks) {
    short8v a2 = *(const short8v*)&mids[(w * 16 + (lane & 15)) * 264 + ks * 32 + kc];
#pragma unroll
    for (int n = 0; n < 4; ++n) {
      short8v bv = *(const short8v*)(const void*)&w2b[(size_t)(n * 16 + (lane & 15)) * 256 + ks * 32 + kc];
      acc2[n] = __builtin_amdgcn_mfma_f32_16x16x32_bf16(a2, bv, acc2[n], 0, 0, 0);
    }
  }
#pragma unroll
  for (int n = 0; n < 4; ++n) {
    const int oc = n * 16 + (lane & 15);
    const float bn = b2[oc];
    const int px = px0 + mrow0;
    const size_t base = (((size_t)(z * 64 + oc)) << 16) + px;
    float4 f = *(const float4*)&feat[base];
    float4 rv;
    rv.x = gelu_f(acc2[n][0] + bn) + f.x;
    rv.y = gelu_f(acc2[n][1] + bn) + f.y;
    rv.z = gelu_f(acc2[n][2] + bn) + f.z;
    rv.w = gelu_f(acc2[n][3] + bn) + f.w;
    *(float4*)&out[base] = rv;
  }
}

extern "C" void kernel_launch(void* const* d_in, const int* in_sizes, int n_in,
                              void* d_out, int out_size, void* d_ws, size_t ws_size,
                              hipStream_t stream) {
  const float* feat  = (const float*)d_in[0];
  const float* w_enc = (const float*)d_in[1];
  const float* b_enc = (const float*)d_in[2];
  const float* w_kc  = (const float*)d_in[3];
  const float* b_kc  = (const float*)d_in[4];
  const float* w_vc  = (const float*)d_in[5];
  const float* b_vc  = (const float*)d_in[6];
  const float* wq    = (const float*)d_in[7];
  const float* bq    = (const float*)d_in[8];
  const float* wk    = (const float*)d_in[9];
  const float* bk    = (const float*)d_in[10];
  const float* gq    = (const float*)d_in[11];
  const float* betaq = (const float*)d_in[12];
  const float* gk    = (const float*)d_in[13];
  const float* betak = (const float*)d_in[14];
  const float* w_f1  = (const float*)d_in[15];
  const float* b_f1  = (const float*)d_in[16];
  const float* w_f2  = (const float*)d_in[17];
  const float* b_f2  = (const float*)d_in[18];

  // ---- workspace schedule, peak ~83 MiB; d_out doubles as scratch ----
  char* ws = (char*)d_ws;
  const size_t MB = (size_t)1 << 20;
  u16*   qun    = (u16*)(ws);                    // 0-32   (dead after merged qk-GEMM)
  u16*   kun    = (u16*)(ws + 32 * MB);          // 32-64  (dead after merged qk-GEMM)
  u16*   qlin   = (u16*)(ws + 64 * MB);          // 64-72  (dead after scores)
  u16*   wqb    = (u16*)(ws + 72 * MB);          // 72-80: wq bf16
  u16*   wT     = (u16*)(ws + 80 * MB);          // 216 KiB
  float* bias192= (float*)(ws + 80 * MB + 224 * 1024);
  float* scaleq = (float*)(ws + 80 * MB + 232 * 1024);
  float* shiftq = scaleq + 1024;
  float* scalek = shiftq + 1024;
  float* shiftk = scalek + 1024;
  u16*   wf1b   = (u16*)(ws + 80 * MB + 512 * 1024);  // 32 KiB
  u16*   wf2b   = (u16*)(ws + 80 * MB + 576 * 1024);  // 32 KiB
  float2* bnpart = (float2*)(ws + 81 * MB);      // 81-83
  u16*   scores = (u16*)(ws);                    // 0-8 (qun dead)
  // foldedT chunks at ws {8,16,24,32} MiB (qun/kun dead)
  u16*   featb  = (u16*)d_out;                   // d_out 0-32 MiB scratch (dead after conv)
  u16*   vT     = (u16*)((char*)d_out + 32 * MB);// d_out 32-64 MiB scratch (dead after mode2)
  u16*   wkb    = (u16*)d_out;                   // d_out 0-8: wk bf16 (featb dead; dead after qk-GEMM)
  u16*   klin   = (u16*)((char*)d_out + 8 * MB); // d_out 8-16: klin (no overlap; dead before ffn)

  const dim3 blk(256);
  const dim3 blk8(512);
  // 1) unified prep: NHWC transform + conv wT/bias + wf1b/wf2b
  prep_k<<<4657, blk, 0, stream>>>(feat, featb, w_enc, w_kc, w_vc, b_enc, b_kc, b_vc,
                                   w_f1, w_f2, wT, bias192, wf1b, wf2b);
  // 2) fused 3-conv MFMA (swizzled LDS + reg-prefetch pipeline) -> qun, kun, vT
  convmfma_k<<<2048, blk, 0, stream>>>(featb, wT, bias192, qun, kun, vT);
  // 3) convert wq->wqb (ws) and wk->wkb (d_out 0-8; featb dead)
  wcvt2_k<<<dim3(4096, 2), blk, 0, stream>>>(wq, wqb, wk, wkb);
  // 4) q+k linear in ONE launch (z=2), BK=32 m97-geometry GEMM; klin -> d_out 8-16
  mgemmL_k<0><<<dim3(8, 32, 2), blk8, 0, stream>>>(qun, wqb, bq, qlin, 4096,
                                                   kun, wkb, bk, klin);
  // 5) BN stats (two-stage parallel)
  bnpart_k<<<dim3(128, 2), blk, 0, stream>>>(qlin, klin, bnpart);
  bnfin_k<<<dim3(4, 2), blk, 0, stream>>>(bnpart, gq, betaq, gk, betak, scaleq, shiftq, scalek, shiftk);
  // 6) scores = BN(q) @ BN(k)^T / 32 (reg-staged, BN fused)
  mgemm1_k<<<dim3(8, 8, 4), blk8, 0, stream>>>(qlin, klin, scaleq, shiftq, scalek, shiftk,
                                               scores, 1024);
  // 7) softmax
  softmax_k<<<4096, blk, 0, stream>>>(scores);
  // 8) attn @ V -> foldedT chunks (BK=32 GEMM, XCD swizzle inside)
  mgemmL_k<2><<<dim3(32, 8, 4), blk8, 0, stream>>>(scores, vT, nullptr, (u16*)ws, 1024,
                                                   nullptr, nullptr, nullptr, nullptr);
  // 9) fused FFN (all batches, one launch; mid lives in LDS)
  ffn_k<<<dim3(512, 4), blk8, 67584, stream>>>((u16*)(ws + 8 * MB), wf1b, wf2b, b_f1, b_f2, feat, (float*)d_out);
  (void)in_sizes; (void)n_in; (void)out_size; (void)ws_size;
}

// Round 19
// 444.916 us; speedup vs baseline: 1.0626x; 1.0626x over previous
//
#include <hip/hip_runtime.h>
#include <hip/hip_bf16.h>

typedef unsigned short u16;
typedef __attribute__((ext_vector_type(8))) short short8v;          // 8 bf16 (4 VGPRs)
typedef __attribute__((ext_vector_type(8))) unsigned short u16x8;   // 8 u16
typedef __attribute__((ext_vector_type(4))) float f32x4;

#define HWPIX 65536  // 256*256
#define AS1(p) ((const __attribute__((address_space(1))) void*)(p))
#define AS3(p) ((__attribute__((address_space(3))) void*)(p))

__device__ __forceinline__ float bfbits2f(u16 u) {
  return __uint_as_float(((unsigned)u) << 16);
}
__device__ __forceinline__ float4 ld4bf(const u16* p) {
  ushort4 u = *(const ushort4*)(const void*)p;
  return make_float4(bfbits2f(u.x), bfbits2f(u.y), bfbits2f(u.z), bfbits2f(u.w));
}
__device__ __forceinline__ u16 f2bf(float f) {
  union { __hip_bfloat16 h; u16 u; } c;
  c.h = __float2bfloat16(f);   // RNE
  return c.u;
}
// tanh-form gelu: |err| <= ~3e-4 abs; reaches d_out only via 0.02^2-damped FFN path.
__device__ __forceinline__ float gelu_f(float x) {
  float z = 0.79788456f * x * (1.0f + 0.044715f * x * x);
  float e = __expf(2.0f * z);
  float th = 1.0f - 2.0f * __builtin_amdgcn_rcpf(e + 1.0f);
  return 0.5f * x * (1.0f + th);
}
// apply BN scale/shift to 8 bf16 at channel kk..kk+7, re-round to bf16
__device__ __forceinline__ u16x8 bn8(u16x8 v, const float* __restrict__ sc,
                                     const float* __restrict__ sh, int kk) {
  float4 s0 = *(const float4*)&sc[kk], s1 = *(const float4*)&sc[kk + 4];
  float4 t0 = *(const float4*)&sh[kk], t1 = *(const float4*)&sh[kk + 4];
  u16x8 r;
  r[0] = f2bf(bfbits2f(v[0]) * s0.x + t0.x); r[1] = f2bf(bfbits2f(v[1]) * s0.y + t0.y);
  r[2] = f2bf(bfbits2f(v[2]) * s0.z + t0.z); r[3] = f2bf(bfbits2f(v[3]) * s0.w + t0.w);
  r[4] = f2bf(bfbits2f(v[4]) * s1.x + t1.x); r[5] = f2bf(bfbits2f(v[5]) * s1.y + t1.y);
  r[6] = f2bf(bfbits2f(v[6]) * s1.z + t1.z); r[7] = f2bf(bfbits2f(v[7]) * s1.w + t1.w);
  return r;
}

// ------ unified prep: nhwc transform (blocks 0..4095) + weight pack/convert (4096..4656) ------
__launch_bounds__(256)
__global__ void prep_k(const float* __restrict__ feat, u16* __restrict__ featb,
                       const float* __restrict__ w0, const float* __restrict__ w1,
                       const float* __restrict__ w2, const float* __restrict__ b0,
                       const float* __restrict__ b1, const float* __restrict__ b2,
                       const float* __restrict__ wf1, const float* __restrict__ wf2,
                       u16* __restrict__ wT, float* __restrict__ bias192,
                       u16* __restrict__ wf1b, u16* __restrict__ wf2b) {
  __shared__ float tile[64][65];
  const int t = threadIdx.x;
  const int bxg = blockIdx.x;
  if (bxg < 4096) {
    const int xs = (bxg & 3) << 6, yy = (bxg >> 2) & 255, b = bxg >> 10;
#pragma unroll
    for (int it = 0; it < 4; ++it) {
      const int idx = t + it * 256;
      const int c = idx >> 4, seg = (idx & 15) << 2;
      float4 v = *(const float4*)&feat[(((size_t)(b * 64 + c)) << 16) + yy * 256 + xs + seg];
      tile[c][seg] = v.x; tile[c][seg + 1] = v.y; tile[c][seg + 2] = v.z; tile[c][seg + 3] = v.w;
    }
    __syncthreads();
#pragma unroll
    for (int it = 0; it < 4; ++it) {
      const int idx = t + it * 256;
      const int cs = (idx & 15) << 2, px = idx >> 4;
      ushort4 r;
      r.x = f2bf(tile[cs + 0][px]); r.y = f2bf(tile[cs + 1][px]);
      r.z = f2bf(tile[cs + 2][px]); r.w = f2bf(tile[cs + 3][px]);
      *(ushort4*)&featb[(((size_t)((b * 256 + yy) * 256 + xs + px)) << 6) + cs] = r;
    }
    return;
  }
  const int bx = bxg - 4096;
  if (bx >= 497) {
    const int e = (bx - 497) * 256 + t;
    wf2b[e] = f2bf(wf2[e]);
    return;
  }
  if (bx >= 433) {
    const int e = (bx - 433) * 256 + t;
    wf1b[e] = f2bf(wf1[e]);
    return;
  }
  if (bx == 432) {
    if (t < 192) {
      const float* bp = (t < 64) ? b0 : (t < 128) ? b1 : b2;
      bias192[t] = bp[t & 63];
    }
    return;
  }
  const int e = bx * 256 + t;
  const int pos = e / 12288, rem = e % 12288;
  const int n = rem >> 6, ic = rem & 63;
  const int conv = n >> 6, oc = n & 63;
  const float* wp = (conv == 0) ? w0 : (conv == 1) ? w1 : w2;
  wT[e] = f2bf(wp[(oc * 64 + ic) * 9 + pos]);
}

// ---------------- f32 -> bf16 bulk convert, dual (z selects src/dst) ----------------
__launch_bounds__(256)
__global__ void wcvt2_k(const float* __restrict__ s0, u16* __restrict__ d0,
                        const float* __restrict__ s1, u16* __restrict__ d1) {
  const float* src = blockIdx.y ? s1 : s0;
  u16* dst = blockIdx.y ? d1 : d0;
  const int i = (blockIdx.x * 256 + threadIdx.x) << 2;
  float4 v = *(const float4*)&src[i];
  ushort4 r;
  r.x = f2bf(v.x); r.y = f2bf(v.y); r.z = f2bf(v.z); r.w = f2bf(v.w);
  *(ushort4*)&dst[i] = r;
}

// ---------------- fused 3-conv implicit GEMM (MFMA), XOR-swizzled LDS + reg-prefetch ----------------
__launch_bounds__(256)
__global__ void convmfma_k(const u16* __restrict__ featb, const u16* __restrict__ wT,
                           const float* __restrict__ bias192, u16* __restrict__ qun,
                           u16* __restrict__ kun, u16* __restrict__ vT) {
  __shared__ u16 As[128 * 64];   // 16 KB
  __shared__ u16 Bs[192 * 64];   // 24 KB
  const int tid = threadIdx.x;
  const int lin = blockIdx.x;
  const int virt = (lin & 7) * 256 + (lin >> 3);
  const int b = virt >> 9, yy = (virt >> 1) & 255, x0 = (virt & 1) << 7;
  const int lane = tid & 63, w = tid >> 6;
  const int wm = w >> 1, wn = w & 1;

  u16x8 rA[4], rB[6];
  auto issue = [&](int pos) {
    const int dy = pos / 3, dx = pos % 3;
    const int yp = yy + dy - 1;
    const bool yok = (unsigned)yp < 256u;
#pragma unroll
    for (int i = 0; i < 4; ++i) {
      const int slot = tid + (i << 8);
      const int row = slot >> 3, cg = slot & 7;
      const int xp = x0 + row + dx - 1;
      u16x8 v{};
      if (yok && (unsigned)xp < 256u)
        v = *(const u16x8*)&featb[(((size_t)((b * 256 + yp) * 256 + xp)) << 6) + (cg << 3)];
      rA[i] = v;
    }
    const u16* wb = wT + (size_t)pos * 12288;
#pragma unroll
    for (int i = 0; i < 6; ++i) {
      const int slot = tid + (i << 8);
      const int row = slot >> 3, cg = slot & 7;
      rB[i] = *(const u16x8*)&wb[(row << 6) + (cg << 3)];
    }
  };
  auto commit = [&]() {
#pragma unroll
    for (int i = 0; i < 4; ++i) {
      const int slot = tid + (i << 8);
      const int row = slot >> 3, cg = slot & 7;
      *(u16x8*)&As[(row << 6) + ((cg ^ (row & 7)) << 3)] = rA[i];
    }
#pragma unroll
    for (int i = 0; i < 6; ++i) {
      const int slot = tid + (i << 8);
      const int row = slot >> 3, cg = slot & 7;
      *(u16x8*)&Bs[(row << 6) + ((cg ^ (row & 7)) << 3)] = rB[i];
    }
  };

  f32x4 acc[4][6] = {};
  const int kc = (lane >> 4) << 3;
  const int afr = wm * 64 + (lane & 15);
  const int bfr0 = wn * 96 + (lane & 15);

  issue(0);
  commit();
  __syncthreads();

  for (int pos = 0; pos < 9; ++pos) {
    if (pos + 1 < 9) issue(pos + 1);
#pragma unroll
    for (int ks = 0; ks < 2; ++ks) {
      const int ce = (ks << 5) + kc;
      short8v a[4], bf[6];
#pragma unroll
      for (int f = 0; f < 4; ++f) {
        const int row = afr + f * 16;
        a[f] = *(const short8v*)&As[(row << 6) + (ce ^ ((row & 7) << 3))];
      }
#pragma unroll
      for (int f = 0; f < 6; ++f) {
        const int row = bfr0 + f * 16;
        bf[f] = *(const short8v*)&Bs[(row << 6) + (ce ^ ((row & 7) << 3))];
      }
#pragma unroll
      for (int i = 0; i < 4; ++i)
#pragma unroll
        for (int j = 0; j < 6; ++j)
          acc[i][j] = __builtin_amdgcn_mfma_f32_16x16x32_bf16(a[i], bf[j], acc[i][j], 0, 0, 0);
    }
    __syncthreads();
    if (pos + 1 < 9) {
      commit();
      __syncthreads();
    }
  }

  const int py = yy >> 3, ky = yy & 7;
  const int rp0 = wm * 64 + ((lane >> 4) << 2);
#pragma unroll
  for (int j = 0; j < 6; ++j) {
    const int colb = wn * 96 + j * 16;
    const int conv = colb >> 6;
    const int oc = (colb & 63) + (lane & 15);
    const float bj = bias192[colb + (lane & 15)];
#pragma unroll
    for (int i = 0; i < 4; ++i) {
      const int rp = rp0 + i * 16;
      const int xg = x0 + rp;
      const int px = xg >> 3, kx0 = xg & 7;
      float v0 = gelu_f(acc[i][j][0] + bj);
      float v1 = gelu_f(acc[i][j][1] + bj);
      float v2 = gelu_f(acc[i][j][2] + bj);
      float v3 = gelu_f(acc[i][j][3] + bj);
      const int d0 = (oc << 6) + (ky << 3) + kx0;
      if (conv < 2) {
        u16* dst = conv ? kun : qun;
        const size_t addr = (((size_t)((b << 10) + py * 32 + px)) << 12) + d0;
        ushort4 r4;
        r4.x = f2bf(v0); r4.y = f2bf(v1); r4.z = f2bf(v2); r4.w = f2bf(v3);
        *(ushort4*)&dst[addr] = r4;
      } else {
        const int m = py * 32 + px;
        const size_t base = (((size_t)(b * 4096 + d0)) << 10) + m;
        vT[base] = f2bf(v0);
        vT[base + 1024] = f2bf(v1);
        vT[base + 2048] = f2bf(v2);
        vT[base + 3072] = f2bf(v3);
      }
    }
  }
}

// ---------------- BN stats, two-stage parallel reduction ----------------
__launch_bounds__(256)
__global__ void bnpart_k(const u16* __restrict__ q, const u16* __restrict__ k,
                         float2* __restrict__ part) {
  const u16* x = blockIdx.y ? k : q;
  const int b = blockIdx.x, t = threadIdx.x;
  const int c = t << 2;
  float s0 = 0.f, s1 = 0.f, s2 = 0.f, s3 = 0.f;
  float q0 = 0.f, q1 = 0.f, q2 = 0.f, q3 = 0.f;
  const u16* base = x + ((size_t)b << 15) + c;
#pragma unroll 4
  for (int r = 0; r < 32; ++r) {
    float4 v = ld4bf(base + (r << 10));
    s0 += v.x; q0 += v.x * v.x;
    s1 += v.y; q1 += v.y * v.y;
    s2 += v.z; q2 += v.z * v.z;
    s3 += v.w; q3 += v.w * v.w;
  }
  float2* dst = part + (((size_t)(blockIdx.y * 128 + b)) << 10) + c;
  dst[0] = make_float2(s0, q0);
  dst[1] = make_float2(s1, q1);
  dst[2] = make_float2(s2, q2);
  dst[3] = make_float2(s3, q3);
}
__launch_bounds__(256)
__global__ void bnfin_k(const float2* __restrict__ part, const float* __restrict__ gq,
                        const float* __restrict__ betaq, const float* __restrict__ gk,
                        const float* __restrict__ betak, float* __restrict__ scq,
                        float* __restrict__ shq, float* __restrict__ sck,
                        float* __restrict__ shk) {
  const int n = blockIdx.x * 256 + threadIdx.x;
  const int y = blockIdx.y;
  const float2* p = part + (((size_t)(y * 128)) << 10) + n;
  float S = 0.f, S2 = 0.f;
  for (int i = 0; i < 128; ++i) {
    float2 v = p[(size_t)i << 10];
    S += v.x; S2 += v.y;
  }
  const float mean = S * (1.0f / 4096.0f);
  const float var = S2 * (1.0f / 4096.0f) - mean * mean;  // biased, matches torch fwd
  const float rstd = rsqrtf(var + 1e-5f);
  const float g = (y ? gk : gq)[n];
  const float be = (y ? betak : betaq)[n];
  const float sc = g * rstd;
  (y ? sck : scq)[n] = sc;
  (y ? shk : shq)[n] = be - mean * sc;
}

// ---------------- row softmax over [4096 rows][1024] bf16 in place ----------------
__launch_bounds__(256)
__global__ void softmax_k(u16* __restrict__ s) {
  u16* p = s + (size_t)blockIdx.x * 1024;
  const int tid = threadIdx.x;
  float4 v = ld4bf(p + (tid << 2));
  float mx = fmaxf(fmaxf(v.x, v.y), fmaxf(v.z, v.w));
#pragma unroll
  for (int off = 32; off > 0; off >>= 1) mx = fmaxf(mx, __shfl_xor(mx, off));
  __shared__ float red[8];
  if ((tid & 63) == 0) red[tid >> 6] = mx;
  __syncthreads();
  mx = fmaxf(fmaxf(red[0], red[1]), fmaxf(red[2], red[3]));
  float e0 = __expf(v.x - mx), e1 = __expf(v.y - mx), e2 = __expf(v.z - mx), e3 = __expf(v.w - mx);
  float sm = e0 + e1 + e2 + e3;
#pragma unroll
  for (int off = 32; off > 0; off >>= 1) sm += __shfl_xor(sm, off);
  if ((tid & 63) == 0) red[4 + (tid >> 6)] = sm;
  __syncthreads();
  sm = red[4] + red[5] + red[6] + red[7];
  float inv = 1.0f / sm;
  ushort4 r;
  r.x = f2bf(e0 * inv); r.y = f2bf(e1 * inv); r.z = f2bf(e2 * inv); r.w = f2bf(e3 * inv);
  *(ushort4*)&p[tid << 2] = r;
}

// ---- 8-wave MFMA GEMM with global_load_lds(16B) + XOR-swizzled LDS (modes 0/2), BK=64 ----
// MODE 0 now also XCD-chunk swizzled (8 n-blocks sharing an A-panel -> same XCD).
template <int MODE>
__launch_bounds__(512)
__global__ void mgemmL_k(const u16* __restrict__ Ap0, const u16* __restrict__ Bp0,
                         const float* __restrict__ bias0, u16* __restrict__ Cp0, int K,
                         const u16* __restrict__ Ap2, const u16* __restrict__ Bp2,
                         const float* __restrict__ bias2, u16* __restrict__ Cp2) {
  constexpr int SD = (MODE == 0) ? 4096 : 1024;
  __shared__ u16 As[2][128 * 64];
  __shared__ u16 Bs[2][128 * 64];
  const int tid = threadIdx.x;

  int bx, by, z;
  if constexpr (MODE == 2) {
    int lin = blockIdx.x + 32 * blockIdx.y + 256 * blockIdx.z;
    int sw = (lin & 7) * 128 + (lin >> 3);
    bx = sw & 31; by = (sw >> 5) & 7; z = sw >> 8;
  } else if constexpr (MODE == 0) {
    // T1: chunk 512 blocks so consecutive virt (same by-panel) land on one XCD
    int lin = blockIdx.x + 8 * blockIdx.y + 256 * blockIdx.z;
    int sw = (lin & 7) * 64 + (lin >> 3);
    bx = sw & 7; by = (sw >> 3) & 31; z = sw >> 8;
  } else {
    bx = blockIdx.x; by = blockIdx.y; z = blockIdx.z;
  }
  const u16* Ap = Ap0;
  const u16* Bp = Bp0;
  const float* bias = bias0;
  u16* Cp = Cp0;
  if constexpr (MODE == 0) {
    if (z) { Ap = Ap2; Bp = Bp2; bias = bias2; Cp = Cp2; }
  }
  const int m0 = by * 128, n0 = bx * 128;
  const int lane = tid & 63, w = tid >> 6;
  const int wm = w >> 2, wn = w & 3;

  const int srow = tid >> 3;                                // 0..63
  const int scol = (((tid & 7) ^ (srow & 7)) << 3);         // swizzled source col (elems)
  const size_t zoffA = (MODE == 0) ? 0 : ((size_t)z << 10);
  const size_t zoffB = (MODE == 0) ? 0 : ((size_t)z << 12);
  const u16* gA0 = Ap + (zoffA + m0 + srow) * (size_t)SD + scol;
  const u16* gA1 = gA0 + (size_t)64 * SD;   // (srow+64)&7 == srow&7 -> same swizzle
  const u16* gB0 = Bp + (zoffB + n0 + srow) * (size_t)SD + scol;
  const u16* gB1 = gB0 + (size_t)64 * SD;
  const int lw0 = (w * 8) * 64;             // wave-uniform LDS element base
  const int lw1 = (64 + w * 8) * 64;

  const int NT = K >> 6;
  __builtin_amdgcn_global_load_lds(AS1(gA0), AS3(&As[0][lw0]), 16, 0, 0);
  __builtin_amdgcn_global_load_lds(AS1(gA1), AS3(&As[0][lw1]), 16, 0, 0);
  __builtin_amdgcn_global_load_lds(AS1(gB0), AS3(&Bs[0][lw0]), 16, 0, 0);
  __builtin_amdgcn_global_load_lds(AS1(gB1), AS3(&Bs[0][lw1]), 16, 0, 0);

  f32x4 acc[4][2] = {};
  const int fr = lane & 15;
  const int kg = (lane >> 4) << 3;
  int cur = 0;
  for (int t = 0; t < NT; ++t) {
    __syncthreads();
    if (t + 1 < NT) {
      const int kn = (t + 1) << 6;
      __builtin_amdgcn_global_load_lds(AS1(gA0 + kn), AS3(&As[cur ^ 1][lw0]), 16, 0, 0);
      __builtin_amdgcn_global_load_lds(AS1(gA1 + kn), AS3(&As[cur ^ 1][lw1]), 16, 0, 0);
      __builtin_amdgcn_global_load_lds(AS1(gB0 + kn), AS3(&Bs[cur ^ 1][lw0]), 16, 0, 0);
      __builtin_amdgcn_global_load_lds(AS1(gB1 + kn), AS3(&Bs[cur ^ 1][lw1]), 16, 0, 0);
    }
    const u16* Asb = As[cur];
    const u16* Bsb = Bs[cur];
#pragma unroll
    for (int ks = 0; ks < 2; ++ks) {
      const int ce = ks * 32 + kg;
      short8v a[4], bfr[2];
#pragma unroll
      for (int f = 0; f < 4; ++f) {
        const int row = wm * 64 + fr + f * 16;
        a[f] = *(const short8v*)&Asb[row * 64 + (ce ^ ((row & 7) << 3))];
      }
#pragma unroll
      for (int f = 0; f < 2; ++f) {
        const int row = wn * 32 + fr + f * 16;
        bfr[f] = *(const short8v*)&Bsb[row * 64 + (ce ^ ((row & 7) << 3))];
      }
#pragma unroll
      for (int i = 0; i < 4; ++i)
#pragma unroll
        for (int j = 0; j < 2; ++j)
          acc[i][j] = __builtin_amdgcn_mfma_f32_16x16x32_bf16(a[i], bfr[j], acc[i][j], 0, 0, 0);
    }
    cur ^= 1;
  }

  const int rowbase = m0 + wm * 64 + ((lane >> 4) << 2);
  const int colbase = n0 + wn * 32 + (lane & 15);
  if constexpr (MODE == 2) {
    const size_t coff = (size_t)(8 + 8 * z) * 524288;  // ws MiB offsets {8,16,24,32} in u16
    u16* C = Cp + coff;
#pragma unroll
    for (int j = 0; j < 2; ++j) {
      const int d = colbase + j * 16;
      const int c = d >> 6, ky = (d >> 3) & 7, kx = d & 7;
#pragma unroll
      for (int i = 0; i < 4; ++i)
#pragma unroll
        for (int r = 0; r < 4; ++r) {
          const int l = rowbase + i * 16 + r;
          const int p = (((l >> 5) << 3) + ky) * 256 + ((l & 31) << 3) + kx;
          C[((size_t)p << 6) + c] = f2bf(acc[i][j][r]);
        }
    }
  } else {
#pragma unroll
    for (int j = 0; j < 2; ++j) {
      const int col = colbase + j * 16;
      const float bj = bias[col];
#pragma unroll
      for (int i = 0; i < 4; ++i)
#pragma unroll
        for (int r = 0; r < 4; ++r)
          Cp[(size_t)(rowbase + i * 16 + r) * 1024 + col] = f2bf(acc[i][j][r] + bj);
    }
  }
}

// ---------------- 8-wave reg-staged MFMA GEMM (MODE 1 only: BN fused at staging) ----------------
__launch_bounds__(512)
__global__ void mgemm1_k(const u16* __restrict__ Ap, const u16* __restrict__ Bp,
                         const float* __restrict__ sA, const float* __restrict__ hA,
                         const float* __restrict__ sB, const float* __restrict__ hB,
                         u16* __restrict__ Cp, int K) {
  constexpr int SD = 1024;
  __shared__ u16 As[2][128 * 72];
  __shared__ u16 Bs[2][128 * 72];
  const int tid = threadIdx.x;
  const int bx = blockIdx.x, by = blockIdx.y, z = blockIdx.z;
  const int m0 = by * 128, n0 = bx * 128;
  const int lane = tid & 63, w = tid >> 6;
  const int wm = w >> 2, wn = w & 3;

  const int srow = tid >> 3;
  const int scol = (tid & 7) << 3;
  const size_t zoff = (size_t)z << 10;
  const u16* A0 = Ap + (zoff + m0 + srow) * (size_t)SD + scol;
  const u16* A1 = A0 + (size_t)64 * SD;
  const u16* B0 = Bp + (zoff + n0 + srow) * (size_t)SD + scol;
  const u16* B1 = B0 + (size_t)64 * SD;
  const int l0 = srow * 72 + scol;
  const int l1 = (srow + 64) * 72 + scol;

  const int NT = K >> 6;
  u16x8 pA0 = bn8(*(const u16x8*)A0, sA, hA, scol);
  u16x8 pA1 = bn8(*(const u16x8*)A1, sA, hA, scol);
  u16x8 pB0 = bn8(*(const u16x8*)B0, sB, hB, scol);
  u16x8 pB1 = bn8(*(const u16x8*)B1, sB, hB, scol);
  *(u16x8*)&As[0][l0] = pA0; *(u16x8*)&As[0][l1] = pA1;
  *(u16x8*)&Bs[0][l0] = pB0; *(u16x8*)&Bs[0][l1] = pB1;
  __syncthreads();

  f32x4 acc[4][2] = {};
  int cur = 0;
  for (int t = 0; t < NT; ++t) {
    const int kn = (t + 1) << 6;
    if (t + 1 < NT) {
      pA0 = *(const u16x8*)(A0 + kn);
      pA1 = *(const u16x8*)(A1 + kn);
      pB0 = *(const u16x8*)(B0 + kn);
      pB1 = *(const u16x8*)(B1 + kn);
    }
    const u16* Asb = As[cur];
    const u16* Bsb = Bs[cur];
#pragma unroll
    for (int ks = 0; ks < 2; ++ks) {
      const int kc = ks * 32 + ((lane >> 4) << 3);
      short8v a[4], bfr[2];
#pragma unroll
      for (int f = 0; f < 4; ++f)
        a[f] = *(const short8v*)&Asb[(wm * 64 + (lane & 15) + f * 16) * 72 + kc];
#pragma unroll
      for (int f = 0; f < 2; ++f)
        bfr[f] = *(const short8v*)&Bsb[(wn * 32 + (lane & 15) + f * 16) * 72 + kc];
#pragma unroll
      for (int i = 0; i < 4; ++i)
#pragma unroll
        for (int j = 0; j < 2; ++j)
          acc[i][j] = __builtin_amdgcn_mfma_f32_16x16x32_bf16(a[i], bfr[j], acc[i][j], 0, 0, 0);
    }
    if (t + 1 < NT) {
      pA0 = bn8(pA0, sA, hA, kn + scol); pA1 = bn8(pA1, sA, hA, kn + scol);
      pB0 = bn8(pB0, sB, hB, kn + scol); pB1 = bn8(pB1, sB, hB, kn + scol);
      *(u16x8*)&As[cur ^ 1][l0] = pA0; *(u16x8*)&As[cur ^ 1][l1] = pA1;
      *(u16x8*)&Bs[cur ^ 1][l0] = pB0; *(u16x8*)&Bs[cur ^ 1][l1] = pB1;
    }
    __syncthreads();
    cur ^= 1;
  }

  const int rowbase = m0 + wm * 64 + ((lane >> 4) << 2);
  const int colbase = n0 + wn * 32 + (lane & 15);
#pragma unroll
  for (int j = 0; j < 2; ++j) {
    const int col = colbase + j * 16;
#pragma unroll
    for (int i = 0; i < 4; ++i)
#pragma unroll
      for (int r = 0; r < 4; ++r) {
        const size_t row = ((size_t)z << 10) + rowbase + i * 16 + r;
        Cp[row * 1024 + col] = f2bf(acc[i][j][r] * 0.03125f);
      }
  }
}

// ---------------- fused FFN: out = gelu(gelu(fold @ W1^T + b1) @ W2^T + b2) + feat ----------------
__launch_bounds__(512)
__global__ void ffn_k(const u16* __restrict__ fold, const u16* __restrict__ w1b,
                      const u16* __restrict__ w2b, const float* __restrict__ b1,
                      const float* __restrict__ b2, const float* __restrict__ feat,
                      float* __restrict__ out) {
  extern __shared__ u16 sh[];
  u16* Ash = sh;              // [128][72]
  u16* W1s = sh + 9216;       // [256][72]
  u16* mids = sh;             // [128][264] aliased after GEMM1
  const int t = threadIdx.x;
  const int px0 = blockIdx.x << 7;
  const int z = blockIdx.y;
  const u16* fz = fold + ((size_t)z << 22);  // chunks 8 MiB apart (4M u16)

  {  // stage A: 128 x 64
    const int row = t >> 2, cs = (t & 3) << 4;
    const u16* src = fz + (((size_t)(px0 + row)) << 6) + cs;
    *(u16x8*)&Ash[row * 72 + cs] = *(const u16x8*)src;
    *(u16x8*)&Ash[row * 72 + cs + 8] = *(const u16x8*)(src + 8);
  }
  {  // stage W1: 256 x 64
    const int row = t >> 1, cs = (t & 1) << 5;
    const u16* src = w1b + (((size_t)row) << 6) + cs;
    *(u16x8*)&W1s[row * 72 + cs] = *(const u16x8*)src;
    *(u16x8*)&W1s[row * 72 + cs + 8] = *(const u16x8*)(src + 8);
    *(u16x8*)&W1s[row * 72 + cs + 16] = *(const u16x8*)(src + 16);
    *(u16x8*)&W1s[row * 72 + cs + 24] = *(const u16x8*)(src + 24);
  }
  __syncthreads();

  const int lane = t & 63, w = t >> 6;
  const int kc = (lane >> 4) << 3;
  const int mrow = w * 16 + (lane & 15);
  f32x4 acc1[16] = {};
  short8v a0 = *(const short8v*)&Ash[mrow * 72 + kc];
  short8v a1 = *(const short8v*)&Ash[mrow * 72 + 32 + kc];
#pragma unroll
  for (int n = 0; n < 16; ++n) {
    const int br = n * 16 + (lane & 15);
    short8v b0 = *(const short8v*)&W1s[br * 72 + kc];
    short8v bv = *(const short8v*)&W1s[br * 72 + 32 + kc];
    acc1[n] = __builtin_amdgcn_mfma_f32_16x16x32_bf16(a0, b0, acc1[n], 0, 0, 0);
    acc1[n] = __builtin_amdgcn_mfma_f32_16x16x32_bf16(a1, bv, acc1[n], 0, 0, 0);
  }
  __syncthreads();  // Ash/W1s dead; sh becomes mids

  const int mrow0 = w * 16 + ((lane >> 4) << 2);
#pragma unroll
  for (int n = 0; n < 16; ++n) {
    const int col = n * 16 + (lane & 15);
    const float bj = b1[col];
#pragma unroll
    for (int r = 0; r < 4; ++r)
      mids[(mrow0 + r) * 264 + col] = f2bf(gelu_f(acc1[n][r] + bj));
  }
  __syncthreads();

  f32x4 acc2[4] = {};
#pragma unroll
  for (int ks = 0; ks < 8; ++ks) {
    short8v a2 = *(const short8v*)&mids[(w * 16 + (lane & 15)) * 264 + ks * 32 + kc];
#pragma unroll
    for (int n = 0; n < 4; ++n) {
      short8v bv = *(const short8v*)(const void*)&w2b[(size_t)(n * 16 + (lane & 15)) * 256 + ks * 32 + kc];
      acc2[n] = __builtin_amdgcn_mfma_f32_16x16x32_bf16(a2, bv, acc2[n], 0, 0, 0);
    }
  }
#pragma unroll
  for (int n = 0; n < 4; ++n) {
    const int oc = n * 16 + (lane & 15);
    const float bn = b2[oc];
    const int px = px0 + mrow0;
    const size_t base = (((size_t)(z * 64 + oc)) << 16) + px;
    float4 f = *(const float4*)&feat[base];
    float4 rv;
    rv.x = gelu_f(acc2[n][0] + bn) + f.x;
    rv.y = gelu_f(acc2[n][1] + bn) + f.y;
    rv.z = gelu_f(acc2[n][2] + bn) + f.z;
    rv.w = gelu_f(acc2[n][3] + bn) + f.w;
    *(float4*)&out[base] = rv;
  }
}

extern "C" void kernel_launch(void* const* d_in, const int* in_sizes, int n_in,
                              void* d_out, int out_size, void* d_ws, size_t ws_size,
                              hipStream_t stream) {
  const float* feat  = (const float*)d_in[0];
  const float* w_enc = (const float*)d_in[1];
  const float* b_enc = (const float*)d_in[2];
  const float* w_kc  = (const float*)d_in[3];
  const float* b_kc  = (const float*)d_in[4];
  const float* w_vc  = (const float*)d_in[5];
  const float* b_vc  = (const float*)d_in[6];
  const float* wq    = (const float*)d_in[7];
  const float* bq    = (const float*)d_in[8];
  const float* wk    = (const float*)d_in[9];
  const float* bk    = (const float*)d_in[10];
  const float* gq    = (const float*)d_in[11];
  const float* betaq = (const float*)d_in[12];
  const float* gk    = (const float*)d_in[13];
  const float* betak = (const float*)d_in[14];
  const float* w_f1  = (const float*)d_in[15];
  const float* b_f1  = (const float*)d_in[16];
  const float* w_f2  = (const float*)d_in[17];
  const float* b_f2  = (const float*)d_in[18];

  // ---- workspace schedule, peak ~83 MiB; d_out doubles as scratch ----
  char* ws = (char*)d_ws;
  const size_t MB = (size_t)1 << 20;
  u16*   qun    = (u16*)(ws);                    // 0-32   (dead after merged qk-GEMM)
  u16*   kun    = (u16*)(ws + 32 * MB);          // 32-64  (dead after merged qk-GEMM)
  u16*   qlin   = (u16*)(ws + 64 * MB);          // 64-72  (dead after scores)
  u16*   wqb    = (u16*)(ws + 72 * MB);          // 72-80: wq bf16
  u16*   wT     = (u16*)(ws + 80 * MB);          // 216 KiB
  float* bias192= (float*)(ws + 80 * MB + 224 * 1024);
  float* scaleq = (float*)(ws + 80 * MB + 232 * 1024);
  float* shiftq = scaleq + 1024;
  float* scalek = shiftq + 1024;
  float* shiftk = scalek + 1024;
  u16*   wf1b   = (u16*)(ws + 80 * MB + 512 * 1024);  // 32 KiB
  u16*   wf2b   = (u16*)(ws + 80 * MB + 576 * 1024);  // 32 KiB
  float2* bnpart = (float2*)(ws + 81 * MB);      // 81-83
  u16*   scores = (u16*)(ws);                    // 0-8 (qun dead)
  // foldedT chunks at ws {8,16,24,32} MiB (qun/kun dead)
  u16*   featb  = (u16*)d_out;                   // d_out 0-32 MiB scratch (dead after conv)
  u16*   vT     = (u16*)((char*)d_out + 32 * MB);// d_out 32-64 MiB scratch (dead after mode2)
  u16*   wkb    = (u16*)d_out;                   // d_out 0-8: wk bf16 (featb dead; dead after qk-GEMM)
  u16*   klin   = (u16*)((char*)d_out + 8 * MB); // d_out 8-16: klin (no overlap; dead before ffn)

  const dim3 blk(256);
  const dim3 blk8(512);
  // 1) unified prep: NHWC transform + conv wT/bias + wf1b/wf2b
  prep_k<<<4657, blk, 0, stream>>>(feat, featb, w_enc, w_kc, w_vc, b_enc, b_kc, b_vc,
                                   w_f1, w_f2, wT, bias192, wf1b, wf2b);
  // 2) fused 3-conv MFMA (swizzled LDS + reg-prefetch pipeline) -> qun, kun, vT
  convmfma_k<<<2048, blk, 0, stream>>>(featb, wT, bias192, qun, kun, vT);
  // 3) convert wq->wqb (ws) and wk->wkb (d_out 0-8; featb dead)
  wcvt2_k<<<dim3(4096, 2), blk, 0, stream>>>(wq, wqb, wk, wkb);
  // 4) q+k linear in ONE launch (z=2), BK=64 gload_lds GEMM + XCD chunking
  mgemmL_k<0><<<dim3(8, 32, 2), blk8, 0, stream>>>(qun, wqb, bq, qlin, 4096,
                                                   kun, wkb, bk, klin);
  // 5) BN stats (two-stage parallel)
  bnpart_k<<<dim3(128, 2), blk, 0, stream>>>(qlin, klin, bnpart);
  bnfin_k<<<dim3(4, 2), blk, 0, stream>>>(bnpart, gq, betaq, gk, betak, scaleq, shiftq, scalek, shiftk);
  // 6) scores = BN(q) @ BN(k)^T / 32 (reg-staged, BN fused)
  mgemm1_k<<<dim3(8, 8, 4), blk8, 0, stream>>>(qlin, klin, scaleq, shiftq, scalek, shiftk,
                                               scores, 1024);
  // 7) softmax
  softmax_k<<<4096, blk, 0, stream>>>(scores);
  // 8) attn @ V -> foldedT chunks (BK=64 GEMM, XCD swizzle inside)
  mgemmL_k<2><<<dim3(32, 8, 4), blk8, 0, stream>>>(scores, vT, nullptr, (u16*)ws, 1024,
                                                   nullptr, nullptr, nullptr, nullptr);
  // 9) fused FFN (all batches, one launch; mid lives in LDS)
  ffn_k<<<dim3(512, 4), blk8, 67584, stream>>>((u16*)(ws + 8 * MB), wf1b, wf2b, b_f1, b_f2, feat, (float*)d_out);
  (void)in_sizes; (void)n_in; (void)out_size; (void)ws_size;
}